// Round 3
// baseline (380.599 us; speedup 1.0000x reference)
//
#include <hip/hip_runtime.h>

// one_hot @ weight where one_hot rows are exact {0,1} one-hot rows.
// Dense GEMM == row gather, bit-exact in fp32.
//
// R2 lesson: one-load-per-thread one-shot blocks ran at ~1.8 TB/s (wave
// replenishment bound, not BW). This version: grid-stride scan with 32
// float4/thread (unroll-4 -> 4 independent loads in flight), zero barriers,
// and the weight-row copy fused in at wave level via ballot+shfl.
//
// Key invariant: a wave's window (64 lanes x float4 = 256 contiguous floats)
// never crosses a row boundary (8192 % 256 == 0), so each wave window holds
// at most ONE hot element -> single ballot + broadcast suffices.

constexpr int N_TOKENS   = 8192;
constexpr int VOCAB      = 8192;          // 2^13
constexpr int D          = 1024;
constexpr int BLOCK      = 256;
constexpr int ITERS      = 32;            // float4 per thread
constexpr long TOTAL_F4  = (long)N_TOKENS * (VOCAB / 4);          // 16,777,216
constexpr int GRID       = (int)(TOTAL_F4 / (BLOCK * ITERS));     // 2048

__global__ __launch_bounds__(BLOCK) void fused_onehot_gather(
    const float* __restrict__ one_hot,
    const float* __restrict__ weight,
    float* __restrict__ out) {
    const int t = threadIdx.x;
    const int lane = t & 63;
    const float4* __restrict__ oh = (const float4*)one_hot;
    // Each block owns a contiguous span of BLOCK*ITERS float4s (= 4 rows).
    const size_t base = (size_t)blockIdx.x * (BLOCK * ITERS);

#pragma unroll 4
    for (int i = 0; i < ITERS; ++i) {
        const size_t e4 = base + (size_t)i * BLOCK + t;
        const float4 v = oh[e4];
        const bool found = (v.x != 0.f) | (v.y != 0.f) |
                           (v.z != 0.f) | (v.w != 0.f);
        const unsigned long long mask = __ballot(found);
        if (mask) {                                   // wave-uniform branch
            // flat element index of the hot '1' (valid on the found lane)
            const int off = (v.x != 0.f) ? 0 : (v.y != 0.f) ? 1
                          : (v.z != 0.f) ? 2 : 3;
            int flat = (int)(e4 * 4) + off;           // < 2^26, fits in int
            const int src = __ffsll(mask) - 1;
            flat = __shfl(flat, src);                 // broadcast to wave
            const int n = flat >> 13;                 // / VOCAB
            const int c = flat & (VOCAB - 1);         // % VOCAB
            // 64 lanes copy weight[c] (1024 floats) -> out[n]: 4 float4/lane
            const float4* __restrict__ wrow = (const float4*)(weight + (size_t)c * D);
            float4* __restrict__ orow = (float4*)(out + (size_t)n * D);
#pragma unroll
            for (int j = 0; j < 4; ++j)
                orow[lane + j * 64] = wrow[lane + j * 64];
        }
    }
}

extern "C" void kernel_launch(void* const* d_in, const int* in_sizes, int n_in,
                              void* d_out, int out_size, void* d_ws, size_t ws_size,
                              hipStream_t stream) {
    const float* one_hot = (const float*)d_in[0];   // [N_TOKENS, VOCAB] f32
    const float* weight  = (const float*)d_in[1];   // [VOCAB, D] f32
    float* out           = (float*)d_out;           // [N_TOKENS, D] f32

    fused_onehot_gather<<<dim3(GRID), dim3(BLOCK), 0, stream>>>(
        one_hot, weight, out);
}

// Round 4
// 357.450 us; speedup vs baseline: 1.0648x; 1.0648x over previous
//
#include <hip/hip_runtime.h>

// one_hot @ weight where one_hot rows are exact {0,1} one-hot rows.
// Dense GEMM == row gather, bit-exact in fp32.
//
// R1-R3 lessons: (a) early exit saves real bytes (R1 fastest residual),
// (b) barriers/LDS-flag exit serialize (R1's flaw), (c) no-exit streaming
// wastes 112 MB (R2/R3). This version: ONE WAVE PER ROW, zero barriers.
// 8192 waves == 256 CU x 32 waves -> entire grid co-resident. Per iter a
// wave loads 4 independent float4/lane (1024 elems = 1/8 row) -> ballot ->
// uniform break. Expected read 56% of 256 MB; weight-row copy fused per wave.

constexpr int N_TOKENS = 8192;
constexpr int VOCAB    = 8192;   // 2^13
constexpr int D        = 1024;
constexpr int BLOCK    = 256;    // 4 waves/block
constexpr int WAVES_PER_BLOCK = BLOCK / 64;
constexpr int ROW_F4   = VOCAB / 4;      // 2048 float4 per row
constexpr int CHUNK_F4 = 64 * 4;         // 256 float4 (=1024 elems) per wave-iter
constexpr int NCHUNK   = ROW_F4 / CHUNK_F4;  // 8

__global__ __launch_bounds__(BLOCK) void wave_row_gather(
    const float* __restrict__ one_hot,
    const float* __restrict__ weight,
    float* __restrict__ out) {
    const int lane = threadIdx.x & 63;
    const int n = blockIdx.x * WAVES_PER_BLOCK + (threadIdx.x >> 6);
    const float4* __restrict__ row = (const float4*)(one_hot + (size_t)n * VOCAB);

    int idx = -1;
    for (int it = 0; it < NCHUNK; ++it) {
        // 4 independent loads in flight (no dependent chain within batch)
        float4 v[4];
#pragma unroll
        for (int j = 0; j < 4; ++j)
            v[j] = row[it * CHUNK_F4 + j * 64 + lane];
        int found = -1;
#pragma unroll
        for (int j = 0; j < 4; ++j) {
            if (v[j].x != 0.f || v[j].y != 0.f || v[j].z != 0.f || v[j].w != 0.f) {
                const int off = (v[j].x != 0.f) ? 0 : (v[j].y != 0.f) ? 1
                              : (v[j].z != 0.f) ? 2 : 3;
                found = (it * CHUNK_F4 + j * 64 + lane) * 4 + off;
            }
        }
        const unsigned long long mask = __ballot(found >= 0);
        if (mask) {                               // wave-uniform
            idx = __shfl(found, __ffsll(mask) - 1);
            break;
        }
    }

    // Copy weight[idx] (1024 floats) -> out[n]: 4 float4 per lane.
    float4* __restrict__ orow = (float4*)(out + (size_t)n * D);
    if (idx >= 0) {
        const float4* __restrict__ wrow = (const float4*)(weight + (size_t)idx * D);
#pragma unroll
        for (int j = 0; j < 4; ++j)
            orow[j * 64 + lane] = wrow[j * 64 + lane];
    } else {
        // all-zero row -> GEMM gives zeros (defensive)
#pragma unroll
        for (int j = 0; j < 4; ++j)
            orow[j * 64 + lane] = make_float4(0.f, 0.f, 0.f, 0.f);
    }
}

extern "C" void kernel_launch(void* const* d_in, const int* in_sizes, int n_in,
                              void* d_out, int out_size, void* d_ws, size_t ws_size,
                              hipStream_t stream) {
    const float* one_hot = (const float*)d_in[0];   // [N_TOKENS, VOCAB] f32
    const float* weight  = (const float*)d_in[1];   // [VOCAB, D] f32
    float* out           = (float*)d_out;           // [N_TOKENS, D] f32

    wave_row_gather<<<dim3(N_TOKENS / WAVES_PER_BLOCK), dim3(BLOCK), 0, stream>>>(
        one_hot, weight, out);
}